// Round 18
// baseline (180.650 us; speedup 1.0000x reference)
//
#include <hip/hip_runtime.h>
#include <hip/hip_bf16.h>

#define NPTS   32768
#define EEDGES 1048576
#define PTSC   1024
#define NCLOUD 32
#define ADIM   132              // per-cloud stride: 128 x + 3 pos + pad
#define MROW   (NCLOUD * ADIM)  // 4224
#define NBLK   256              // contract partial blocks
#define CHUNK  (NPTS / NBLK)    // 128
#define FXSCALE 16777216.0f     // 2^24

// ---------------- weight transpose prep: dst[c*R + r] = src[r*C + c] ----------------
__global__ __launch_bounds__(256) void prep_kernel(
    const float* __restrict__ w2, const float* __restrict__ w3,
    const float* __restrict__ locw, const float* __restrict__ globw,
    const float* __restrict__ d1w, const float* __restrict__ d2w,
    const float* __restrict__ d3w,
    float* __restrict__ w2T, float* __restrict__ w3T,
    float* __restrict__ locT, float* __restrict__ globT,
    float* __restrict__ d1T, float* __restrict__ d2T, float* __restrict__ d3T) {
  int idx = blockIdx.x * 256 + threadIdx.x;
  const float* src; float* dst; int R, C;
  if (idx < 4096)        { src = w2;   dst = w2T;   R = 64;  C = 64;  }
  else if (idx < 12288)  { src = w3;   dst = w3T;   R = 128; C = 64;  idx -= 4096; }
  else if (idx < 45824)  { src = locw; dst = locT;  R = 256; C = 131; idx -= 12288; }
  else if (idx < 144128) { src = globw;dst = globT; R = 384; C = 256; idx -= 45824; }
  else if (idx < 242432) { src = d1w;  dst = d1T;   R = 256; C = 384; idx -= 144128; }
  else if (idx < 275200) { src = d2w;  dst = d2T;   R = 128; C = 256; idx -= 242432; }
  else                   { src = d3w;  dst = d3T;   R = 16;  C = 128; idx -= 275200; }
  int c = idx / R, r = idx % R;
  dst[idx] = src[r * C + c];
}

__device__ __forceinline__ unsigned pack_bf16(float a, float b) {
  __hip_bfloat162 o;
  o.x = __float2bfloat16(a);
  o.y = __float2bfloat16(b);
  return *reinterpret_cast<unsigned*>(&o);
}

__device__ __forceinline__ float rlane(float x, int k) {
  return __int_as_float(__builtin_amdgcn_readlane(__float_as_int(x), k));
}

// fast tanh: 1 - 2/(exp(2x)+1)  — v_exp + v_rcp, ~6 insts, saturates correctly
__device__ __forceinline__ float fast_tanh(float x) {
  float e = __expf(2.0f * x);
  return 1.0f - 2.0f * __builtin_amdgcn_rcpf(e + 1.0f);
}

// ---------------- encoder: 8 pts/wave, in-loop weight loads, readlane broadcasts ----
__global__ __launch_bounds__(256) void enc_kernel(
    const float* __restrict__ pos,
    const float* __restrict__ w1, const float* __restrict__ b1,
    const float* __restrict__ w2T, const float* __restrict__ b2,
    const float* __restrict__ w3T, const float* __restrict__ b3,
    __hip_bfloat16* __restrict__ xb) {
  int wid  = (blockIdx.x * blockDim.x + threadIdx.x) >> 6;
  int lane = threadIdx.x & 63;
  int i0 = __builtin_amdgcn_readfirstlane(wid * 8);   // wave-uniform point base

  float w1a = w1[lane * 3 + 0], w1b = w1[lane * 3 + 1], w1c = w1[lane * 3 + 2];
  float bb1 = b1[lane];

  float h1[8];
#pragma unroll
  for (int p = 0; p < 8; ++p) {
    int i = i0 + p;
    float px = pos[i * 3 + 0], py = pos[i * 3 + 1], pz = pos[i * 3 + 2];  // scalar loads
    h1[p] = fast_tanh(w1a * px + w1b * py + w1c * pz + bb1);
  }

  float bb2 = b2[lane];
  float acc2[8];
#pragma unroll
  for (int p = 0; p < 8; ++p) acc2[p] = bb2;
#pragma unroll
  for (int k = 0; k < 64; ++k) {
    float w = w2T[k * 64 + lane];               // coalesced, L1-resident
#pragma unroll
    for (int p = 0; p < 8; ++p) acc2[p] += w * rlane(h1[p], k);
  }
  float h2[8];
#pragma unroll
  for (int p = 0; p < 8; ++p) h2[p] = fast_tanh(acc2[p]);

  int r0 = 2 * lane;
  float bb3a = b3[r0], bb3b = b3[r0 + 1];
  float acc3a[8], acc3b[8];
#pragma unroll
  for (int p = 0; p < 8; ++p) { acc3a[p] = bb3a; acc3b[p] = bb3b; }
#pragma unroll
  for (int k = 0; k < 64; ++k) {
    float2 w = *reinterpret_cast<const float2*>(w3T + k * 128 + r0);  // coalesced
#pragma unroll
    for (int p = 0; p < 8; ++p) {
      float h = rlane(h2[p], k);
      acc3a[p] += w.x * h;
      acc3b[p] += w.y * h;
    }
  }
#pragma unroll
  for (int p = 0; p < 8; ++p) {
    int i = i0 + p;
    unsigned o = pack_bf16(fast_tanh(acc3a[p]), fast_tanh(acc3b[p]));
    *reinterpret_cast<unsigned*>(xb + (size_t)i * 128 + r0) = o;
  }
}

// ---------------- degree histogram ----------------
__global__ __launch_bounds__(256) void hist_kernel(const int* __restrict__ ei,
                                                   int* __restrict__ cnt) {
  int t = blockIdx.x * 256 + threadIdx.x;
  const int4* d4 = reinterpret_cast<const int4*>(ei + EEDGES);
  int4 v = d4[t];
  atomicAdd(&cnt[v.x], 1);
  atomicAdd(&cnt[v.y], 1);
  atomicAdd(&cnt[v.z], 1);
  atomicAdd(&cnt[v.w], 1);
}

// invwi + full alpha-row init (zeros + self-loop diagonal) — replaces ai memset
__global__ __launch_bounds__(256) void invwi_kernel(const int* __restrict__ cnt,
                                                    int* __restrict__ invwi,
                                                    int* __restrict__ ai) {
  int i = blockIdx.x * 256 + threadIdx.x;
  int v = (int)rintf(FXSCALE / (float)(cnt[i] + 1));
  invwi[i] = v;
  int4 z = make_int4(0, 0, 0, 0);
  int4* row = reinterpret_cast<int4*>(ai + i * 32);
#pragma unroll
  for (int q = 0; q < 8; ++q) row[q] = z;
  ai[i * 32 + (i >> 10)] = v;   // self-loop contribution
}

// ---------------- alpha scatter (edges only): 4 edges/thread for MLP ----------------
__global__ __launch_bounds__(256) void ascatter_kernel(const int* __restrict__ ei,
                                                       const int* __restrict__ invwi,
                                                       int* __restrict__ ai) {
  int t = blockIdx.x * 256 + threadIdx.x;   // t < EEDGES/4
  const int4* s4 = reinterpret_cast<const int4*>(ei);
  const int4* d4 = reinterpret_cast<const int4*>(ei + EEDGES);
  int4 s = s4[t];
  int4 d = d4[t];
  int w0 = invwi[d.x];          // 4 independent random loads in flight
  int w1 = invwi[d.y];
  int w2 = invwi[d.z];
  int w3 = invwi[d.w];
  atomicAdd(&ai[s.x * 32 + (d.x >> 10)], w0);
  atomicAdd(&ai[s.y * 32 + (d.y >> 10)], w1);
  atomicAdd(&ai[s.z * 32 + (d.z >> 10)], w2);
  atomicAdd(&ai[s.w * 32 + (d.w >> 10)], w3);
}

// ---------------- contraction: partial[b][c][dim] = sum_s alpha[s][c]*X[s][dim] ----------------
__global__ __launch_bounds__(256) void contract_kernel(
    const ushort* __restrict__ xu, const float* __restrict__ pos,
    const int* __restrict__ ai, float* __restrict__ partial) {
  int w = threadIdx.x >> 6, l = threadIdx.x & 63;
  int cw = w * 8;
  int s0 = blockIdx.x * CHUNK;
  int s1 = s0 + CHUNK;

  float a0[8] = {0,0,0,0,0,0,0,0};
  float a1[8] = {0,0,0,0,0,0,0,0};
  float a2[8] = {0,0,0,0,0,0,0,0};

#pragma unroll 2
  for (int s = s0; s < s1; ++s) {
    unsigned xr = *reinterpret_cast<const unsigned*>(xu + (size_t)s * 128 + 2 * l);
    float f0 = __uint_as_float(xr << 16);
    float f1 = __uint_as_float(xr & 0xffff0000u);
    float p  = (l < 3) ? pos[s * 3 + l] : 0.f;
    const int4* ar = reinterpret_cast<const int4*>(ai + (size_t)s * 32 + cw);
    int4 A0 = ar[0], A1 = ar[1];
    float af[8] = {(float)A0.x, (float)A0.y, (float)A0.z, (float)A0.w,
                   (float)A1.x, (float)A1.y, (float)A1.z, (float)A1.w};
#pragma unroll
    for (int cc = 0; cc < 8; ++cc) {
      a0[cc] += af[cc] * f0;
      a1[cc] += af[cc] * f1;
      a2[cc] += af[cc] * p;
    }
  }

  const float SC = 1.0f / FXSCALE;
  float* pb = partial + (size_t)blockIdx.x * MROW;
#pragma unroll
  for (int cc = 0; cc < 8; ++cc) {
    pb[(cw + cc) * ADIM + 2 * l]     = a0[cc] * SC;
    pb[(cw + cc) * ADIM + 2 * l + 1] = a1[cc] * SC;
    if (l < 3) pb[(cw + cc) * ADIM + 128 + l] = a2[cc] * SC;
  }
}

// ---------------- reduce: one wave per idx, shfl tree ----------------
__global__ __launch_bounds__(256) void reduce_kernel(const float* __restrict__ partial,
                                                     float* __restrict__ Macc) {
  int w = threadIdx.x >> 6, l = threadIdx.x & 63;
  int idx = blockIdx.x * 4 + w;
  if (idx >= MROW) return;
  float s = 0.f;
#pragma unroll
  for (int b = 0; b < NBLK; b += 64)
    s += partial[(size_t)(b + l) * MROW + idx];
  s += __shfl_xor(s, 32);
  s += __shfl_xor(s, 16);
  s += __shfl_xor(s, 8);
  s += __shfl_xor(s, 4);
  s += __shfl_xor(s, 2);
  s += __shfl_xor(s, 1);
  if (l == 0) Macc[idx] = s;
}

// ---------------- tail MLP: 1 block/cloud, 1024 threads, float4-batched deep k-split ----
__global__ __launch_bounds__(1024) void final_kernel(
    const float* __restrict__ Macc, const float* __restrict__ pos,
    const float* __restrict__ locT, const float* __restrict__ loc_b,
    const float* __restrict__ globT, const float* __restrict__ glob_b,
    const float* __restrict__ d1T, const float* __restrict__ d1b,
    const float* __restrict__ d2T, const float* __restrict__ d2b,
    const float* __restrict__ d3T, const float* __restrict__ d3b,
    float* __restrict__ out) {
  int c = blockIdx.x, t = threadIdx.x;
  int wv = t >> 6, ln = t & 63;

  __shared__ float sw[16][3];
  __shared__ float possum[3];
  __shared__ float msh[144];
  __shared__ float ttsh[256];
  __shared__ float ush[384];
  __shared__ float ash[256];
  __shared__ float bvsh[128];
  __shared__ float ptl2[4352];   // k-split partial scratch (padded layouts)

  // --- pos sum ---
  {
    const float* pr = pos + ((size_t)c * PTSC + t) * 3;
    float s0 = pr[0], s1 = pr[1], s2 = pr[2];
#pragma unroll
    for (int m_ = 32; m_ > 0; m_ >>= 1) {
      s0 += __shfl_xor(s0, m_);
      s1 += __shfl_xor(s1, m_);
      s2 += __shfl_xor(s2, m_);
    }
    if (ln == 0) { sw[wv][0] = s0; sw[wv][1] = s1; sw[wv][2] = s2; }
  }
  __syncthreads();
  if (t < 48) {
    int d = t >> 4, idx = t & 15;
    float v = sw[idx][d];
#pragma unroll
    for (int m_ = 8; m_ > 0; m_ >>= 1) v += __shfl_xor(v, m_);
    if (idx == 0) possum[d] = v;
  }
  __syncthreads();

  if (t < 128)       msh[t] = Macc[c * ADIM + t] * (1.0f / (float)PTSC);
  else if (t < 131)  msh[t] = (Macc[c * ADIM + t] - possum[t - 128]) * (1.0f / (float)PTSC);
  else if (t < 144)  msh[t] = 0.f;   // pad rows (weights read from globT region, x0)
  __syncthreads();

  // --- loc: O=256, K=144(pad), ksplit=16 (p=wave), og=lane, 9 batched float4 loads ---
  {
    int p = wv, og = ln;
    float4 wvv[9];
#pragma unroll
    for (int j = 0; j < 9; ++j) {
      int k = p * 9 + j;
      wvv[j] = *reinterpret_cast<const float4*>(locT + (size_t)k * 256 + og * 4);
    }
    float a0, a1, a2, a3;
    if (p == 0) {
      float4 b = *reinterpret_cast<const float4*>(loc_b + og * 4);
      a0 = b.x; a1 = b.y; a2 = b.z; a3 = b.w;
    } else { a0 = a1 = a2 = a3 = 0.f; }
#pragma unroll
    for (int j = 0; j < 9; ++j) {
      float x = msh[p * 9 + j];
      a0 += wvv[j].x * x; a1 += wvv[j].y * x; a2 += wvv[j].z * x; a3 += wvv[j].w * x;
    }
    ptl2[(p * 4 + 0) * 66 + og] = a0;
    ptl2[(p * 4 + 1) * 66 + og] = a1;
    ptl2[(p * 4 + 2) * 66 + og] = a2;
    ptl2[(p * 4 + 3) * 66 + og] = a3;
  }
  __syncthreads();
  if (t < 256) {
    int og = t >> 2, sub = t & 3;
    float s = 0.f;
#pragma unroll
    for (int p = 0; p < 16; ++p) s += ptl2[(p * 4 + sub) * 66 + og];
    ttsh[t] = s;
  }
  __syncthreads();

  // --- glob: O=384, K=256, ksplit=8, og=0..95, 4 batches of 8 float4 loads ---
  if (t < 768) {
    int p = t / 96, og = t - p * 96;
    float a0, a1, a2, a3;
    if (p == 0) {
      float4 b = *reinterpret_cast<const float4*>(glob_b + og * 4);
      a0 = b.x; a1 = b.y; a2 = b.z; a3 = b.w;
    } else { a0 = a1 = a2 = a3 = 0.f; }
#pragma unroll
    for (int B = 0; B < 4; ++B) {
      float4 wvv[8];
#pragma unroll
      for (int j = 0; j < 8; ++j) {
        int k = p * 32 + B * 8 + j;
        wvv[j] = *reinterpret_cast<const float4*>(globT + (size_t)k * 384 + og * 4);
      }
#pragma unroll
      for (int j = 0; j < 8; ++j) {
        float x = ttsh[p * 32 + B * 8 + j];
        a0 += wvv[j].x * x; a1 += wvv[j].y * x; a2 += wvv[j].z * x; a3 += wvv[j].w * x;
      }
    }
    ptl2[(p * 4 + 0) * 98 + og] = a0;
    ptl2[(p * 4 + 1) * 98 + og] = a1;
    ptl2[(p * 4 + 2) * 98 + og] = a2;
    ptl2[(p * 4 + 3) * 98 + og] = a3;
  }
  __syncthreads();
  if (t < 384) {
    int og = t >> 2, sub = t & 3;
    float s = 0.f;
#pragma unroll
    for (int p = 0; p < 8; ++p) s += ptl2[(p * 4 + sub) * 98 + og];
    ush[t] = s;
  }
  __syncthreads();

  // --- d1: O=256, K=384, ksplit=16, 3 batches of 8 float4 loads, tanh ---
  {
    int p = wv, og = ln;
    float a0, a1, a2, a3;
    if (p == 0) {
      float4 b = *reinterpret_cast<const float4*>(d1b + og * 4);
      a0 = b.x; a1 = b.y; a2 = b.z; a3 = b.w;
    } else { a0 = a1 = a2 = a3 = 0.f; }
#pragma unroll
    for (int B = 0; B < 3; ++B) {
      float4 wvv[8];
#pragma unroll
      for (int j = 0; j < 8; ++j) {
        int k = p * 24 + B * 8 + j;
        wvv[j] = *reinterpret_cast<const float4*>(d1T + (size_t)k * 256 + og * 4);
      }
#pragma unroll
      for (int j = 0; j < 8; ++j) {
        float x = ush[p * 24 + B * 8 + j];
        a0 += wvv[j].x * x; a1 += wvv[j].y * x; a2 += wvv[j].z * x; a3 += wvv[j].w * x;
      }
    }
    ptl2[(p * 4 + 0) * 66 + og] = a0;
    ptl2[(p * 4 + 1) * 66 + og] = a1;
    ptl2[(p * 4 + 2) * 66 + og] = a2;
    ptl2[(p * 4 + 3) * 66 + og] = a3;
  }
  __syncthreads();
  if (t < 256) {
    int og = t >> 2, sub = t & 3;
    float s = 0.f;
#pragma unroll
    for (int p = 0; p < 16; ++p) s += ptl2[(p * 4 + sub) * 66 + og];
    ash[t] = tanhf(s);
  }
  __syncthreads();

  // --- d2: O=128, K=256, ksplit=32, og=0..31, 8 batched float4 loads, tanh ---
  {
    int p = t >> 5, og = t & 31;
    float4 wvv[8];
#pragma unroll
    for (int j = 0; j < 8; ++j) {
      int k = p * 8 + j;
      wvv[j] = *reinterpret_cast<const float4*>(d2T + (size_t)k * 128 + og * 4);
    }
    float a0, a1, a2, a3;
    if (p == 0) {
      float4 b = *reinterpret_cast<const float4*>(d2b + og * 4);
      a0 = b.x; a1 = b.y; a2 = b.z; a3 = b.w;
    } else { a0 = a1 = a2 = a3 = 0.f; }
#pragma unroll
    for (int j = 0; j < 8; ++j) {
      float x = ash[p * 8 + j];
      a0 += wvv[j].x * x; a1 += wvv[j].y * x; a2 += wvv[j].z * x; a3 += wvv[j].w * x;
    }
    ptl2[(p * 4 + 0) * 34 + og] = a0;
    ptl2[(p * 4 + 1) * 34 + og] = a1;
    ptl2[(p * 4 + 2) * 34 + og] = a2;
    ptl2[(p * 4 + 3) * 34 + og] = a3;
  }
  __syncthreads();
  if (t < 128) {
    int og = t >> 2, sub = t & 3;
    float s = 0.f;
#pragma unroll
    for (int p = 0; p < 32; ++p) s += ptl2[(p * 4 + sub) * 34 + og];
    bvsh[t] = tanhf(s);
  }
  __syncthreads();

  // --- d3: O=16, K=128, one wave per output ---
  {
    int o = wv, k = ln;
    float acc = d3T[k * 16 + o] * bvsh[k] + d3T[(k + 64) * 16 + o] * bvsh[k + 64];
#pragma unroll
    for (int m_ = 32; m_ > 0; m_ >>= 1) acc += __shfl_xor(acc, m_);
    if (ln == 0) out[c * 16 + o] = acc + d3b[o];
  }
}

extern "C" void kernel_launch(void* const* d_in, const int* in_sizes, int n_in,
                              void* d_out, int out_size, void* d_ws, size_t ws_size,
                              hipStream_t stream) {
  const float* pos    = (const float*)d_in[0];
  const int*   ei     = (const int*)d_in[1];
  const float* enc1_w = (const float*)d_in[2];
  const float* enc1_b = (const float*)d_in[3];
  const float* enc2_w = (const float*)d_in[4];
  const float* enc2_b = (const float*)d_in[5];
  const float* enc3_w = (const float*)d_in[6];
  const float* enc3_b = (const float*)d_in[7];
  const float* loc_w  = (const float*)d_in[8];
  const float* loc_b  = (const float*)d_in[9];
  const float* glob_w = (const float*)d_in[10];
  const float* glob_b = (const float*)d_in[11];
  const float* d1w    = (const float*)d_in[12];
  const float* d1b    = (const float*)d_in[13];
  const float* d2w    = (const float*)d_in[14];
  const float* d2b    = (const float*)d_in[15];
  const float* d3w    = (const float*)d_in[16];
  const float* d3b    = (const float*)d_in[17];
  float* out = (float*)d_out;

  // workspace layout (bytes, 256B-aligned)
  char* ws = (char*)d_ws;
  size_t o = 0;
  __hip_bfloat16* xb = (__hip_bfloat16*)(ws + o); o += 8388608;     // N*128 bf16
  int*   ai    = (int*)  (ws + o); o += 4194304;                    // N*32 i32
  int*   cnt   = (int*)  (ws + o); o += 131072;
  int*   invwi = (int*)  (ws + o); o += 131072;
  float* Macc  = (float*)(ws + o); o += 17408;                      // MROW padded
  float* w2T   = (float*)(ws + o); o += 16384;
  float* w3T   = (float*)(ws + o); o += 32768;
  float* locT  = (float*)(ws + o); o += 134144;
  float* globT = (float*)(ws + o); o += 393216;
  float* d1T   = (float*)(ws + o); o += 393216;
  float* d2T   = (float*)(ws + o); o += 131072;
  float* d3T   = (float*)(ws + o); o += 8192;
  float* partial = (float*)(ws + o);                                // NBLK*MROW f32
  (void)ws_size;

  hipMemsetAsync(cnt, 0, NPTS * sizeof(int), stream);

  prep_kernel<<<1083, 256, 0, stream>>>(enc2_w, enc3_w, loc_w, glob_w, d1w, d2w, d3w,
                                        w2T, w3T, locT, globT, d1T, d2T, d3T);
  hist_kernel<<<EEDGES / 1024, 256, 0, stream>>>(ei, cnt);
  invwi_kernel<<<NPTS / 256, 256, 0, stream>>>(cnt, invwi, ai);
  enc_kernel<<<NPTS / 32, 256, 0, stream>>>(pos, enc1_w, enc1_b, w2T, enc2_b,
                                            w3T, enc3_b, xb);
  ascatter_kernel<<<EEDGES / 1024, 256, 0, stream>>>(ei, invwi, ai);
  contract_kernel<<<NBLK, 256, 0, stream>>>((const ushort*)xb, pos, ai, partial);
  reduce_kernel<<<MROW / 4, 256, 0, stream>>>(partial, Macc);
  final_kernel<<<NCLOUD, 1024, 0, stream>>>(Macc, pos, locT, loc_b, globT, glob_b,
                                            d1T, d1b, d2T, d2b, d3T, d3b, out);
}

// Round 19
// 176.291 us; speedup vs baseline: 1.0247x; 1.0247x over previous
//
#include <hip/hip_runtime.h>
#include <hip/hip_bf16.h>

#define NPTS   32768
#define EEDGES 1048576
#define PTSC   1024
#define NCLOUD 32
#define ADIM   132              // per-cloud stride: 128 x + 3 pos + pad
#define MROW   (NCLOUD * ADIM)  // 4224
#define NBLK   256              // contract partial blocks
#define CHUNK  (NPTS / NBLK)    // 128
#define FXSCALE 16777216.0f     // 2^24

// ---------------- weight transpose prep + cnt zeroing ----------------
// idx < 277248: dst[c*R + r] = src[r*C + c]; idx 277248..310015: cnt[idx-277248] = 0
__global__ __launch_bounds__(256) void prep_kernel(
    const float* __restrict__ w2, const float* __restrict__ w3,
    const float* __restrict__ locw, const float* __restrict__ globw,
    const float* __restrict__ d1w, const float* __restrict__ d2w,
    const float* __restrict__ d3w,
    float* __restrict__ w2T, float* __restrict__ w3T,
    float* __restrict__ locT, float* __restrict__ globT,
    float* __restrict__ d1T, float* __restrict__ d2T, float* __restrict__ d3T,
    int* __restrict__ cnt) {
  int idx = blockIdx.x * 256 + threadIdx.x;
  if (idx >= 277248) {
    cnt[idx - 277248] = 0;
    return;
  }
  const float* src; float* dst; int R, C;
  if (idx < 4096)        { src = w2;   dst = w2T;   R = 64;  C = 64;  }
  else if (idx < 12288)  { src = w3;   dst = w3T;   R = 128; C = 64;  idx -= 4096; }
  else if (idx < 45824)  { src = locw; dst = locT;  R = 256; C = 131; idx -= 12288; }
  else if (idx < 144128) { src = globw;dst = globT; R = 384; C = 256; idx -= 45824; }
  else if (idx < 242432) { src = d1w;  dst = d1T;   R = 256; C = 384; idx -= 144128; }
  else if (idx < 275200) { src = d2w;  dst = d2T;   R = 128; C = 256; idx -= 242432; }
  else                   { src = d3w;  dst = d3T;   R = 16;  C = 128; idx -= 275200; }
  int c = idx / R, r = idx % R;
  dst[idx] = src[r * C + c];
}

__device__ __forceinline__ unsigned pack_bf16(float a, float b) {
  __hip_bfloat162 o;
  o.x = __float2bfloat16(a);
  o.y = __float2bfloat16(b);
  return *reinterpret_cast<unsigned*>(&o);
}

__device__ __forceinline__ float rlane(float x, int k) {
  return __int_as_float(__builtin_amdgcn_readlane(__float_as_int(x), k));
}

// fast tanh: 1 - 2/(exp(2x)+1)  — v_exp + v_rcp, ~6 insts, saturates correctly
__device__ __forceinline__ float fast_tanh(float x) {
  float e = __expf(2.0f * x);
  return 1.0f - 2.0f * __builtin_amdgcn_rcpf(e + 1.0f);
}

// ---------------- encoder: 8 pts/wave, in-loop weight loads, readlane broadcasts ----
__global__ __launch_bounds__(256) void enc_kernel(
    const float* __restrict__ pos,
    const float* __restrict__ w1, const float* __restrict__ b1,
    const float* __restrict__ w2T, const float* __restrict__ b2,
    const float* __restrict__ w3T, const float* __restrict__ b3,
    __hip_bfloat16* __restrict__ xb) {
  int wid  = (blockIdx.x * blockDim.x + threadIdx.x) >> 6;
  int lane = threadIdx.x & 63;
  int i0 = __builtin_amdgcn_readfirstlane(wid * 8);   // wave-uniform point base

  float w1a = w1[lane * 3 + 0], w1b = w1[lane * 3 + 1], w1c = w1[lane * 3 + 2];
  float bb1 = b1[lane];

  float h1[8];
#pragma unroll
  for (int p = 0; p < 8; ++p) {
    int i = i0 + p;
    float px = pos[i * 3 + 0], py = pos[i * 3 + 1], pz = pos[i * 3 + 2];  // scalar loads
    h1[p] = fast_tanh(w1a * px + w1b * py + w1c * pz + bb1);
  }

  float bb2 = b2[lane];
  float acc2[8];
#pragma unroll
  for (int p = 0; p < 8; ++p) acc2[p] = bb2;
#pragma unroll
  for (int k = 0; k < 64; ++k) {
    float w = w2T[k * 64 + lane];               // coalesced, L1-resident
#pragma unroll
    for (int p = 0; p < 8; ++p) acc2[p] += w * rlane(h1[p], k);
  }
  float h2[8];
#pragma unroll
  for (int p = 0; p < 8; ++p) h2[p] = fast_tanh(acc2[p]);

  int r0 = 2 * lane;
  float bb3a = b3[r0], bb3b = b3[r0 + 1];
  float acc3a[8], acc3b[8];
#pragma unroll
  for (int p = 0; p < 8; ++p) { acc3a[p] = bb3a; acc3b[p] = bb3b; }
#pragma unroll
  for (int k = 0; k < 64; ++k) {
    float2 w = *reinterpret_cast<const float2*>(w3T + k * 128 + r0);  // coalesced
#pragma unroll
    for (int p = 0; p < 8; ++p) {
      float h = rlane(h2[p], k);
      acc3a[p] += w.x * h;
      acc3b[p] += w.y * h;
    }
  }
#pragma unroll
  for (int p = 0; p < 8; ++p) {
    int i = i0 + p;
    unsigned o = pack_bf16(fast_tanh(acc3a[p]), fast_tanh(acc3b[p]));
    *reinterpret_cast<unsigned*>(xb + (size_t)i * 128 + r0) = o;
  }
}

// ---------------- degree histogram ----------------
__global__ __launch_bounds__(256) void hist_kernel(const int* __restrict__ ei,
                                                   int* __restrict__ cnt) {
  int t = blockIdx.x * 256 + threadIdx.x;
  const int4* d4 = reinterpret_cast<const int4*>(ei + EEDGES);
  int4 v = d4[t];
  atomicAdd(&cnt[v.x], 1);
  atomicAdd(&cnt[v.y], 1);
  atomicAdd(&cnt[v.z], 1);
  atomicAdd(&cnt[v.w], 1);
}

// invwi + full alpha-row init (zeros + self-loop diagonal) — replaces ai memset
__global__ __launch_bounds__(256) void invwi_kernel(const int* __restrict__ cnt,
                                                    int* __restrict__ invwi,
                                                    int* __restrict__ ai) {
  int i = blockIdx.x * 256 + threadIdx.x;
  int v = (int)rintf(FXSCALE / (float)(cnt[i] + 1));
  invwi[i] = v;
  int4 z = make_int4(0, 0, 0, 0);
  int4* row = reinterpret_cast<int4*>(ai + i * 32);
#pragma unroll
  for (int q = 0; q < 8; ++q) row[q] = z;
  ai[i * 32 + (i >> 10)] = v;   // self-loop contribution
}

// ---------------- alpha scatter (edges only): 4 edges/thread ----------------
__global__ __launch_bounds__(256) void ascatter_kernel(const int* __restrict__ ei,
                                                       const int* __restrict__ invwi,
                                                       int* __restrict__ ai) {
  int t = blockIdx.x * 256 + threadIdx.x;   // t < EEDGES/4
  const int4* s4 = reinterpret_cast<const int4*>(ei);
  const int4* d4 = reinterpret_cast<const int4*>(ei + EEDGES);
  int4 s = s4[t];
  int4 d = d4[t];
  int w0 = invwi[d.x];          // 4 independent random loads in flight
  int w1 = invwi[d.y];
  int w2 = invwi[d.z];
  int w3 = invwi[d.w];
  atomicAdd(&ai[s.x * 32 + (d.x >> 10)], w0);
  atomicAdd(&ai[s.y * 32 + (d.y >> 10)], w1);
  atomicAdd(&ai[s.z * 32 + (d.z >> 10)], w2);
  atomicAdd(&ai[s.w * 32 + (d.w >> 10)], w3);
}

// ---------------- contraction: partial[b][c][dim] = sum_s alpha[s][c]*X[s][dim] ----------------
__global__ __launch_bounds__(256) void contract_kernel(
    const ushort* __restrict__ xu, const float* __restrict__ pos,
    const int* __restrict__ ai, float* __restrict__ partial) {
  int w = threadIdx.x >> 6, l = threadIdx.x & 63;
  int cw = w * 8;
  int s0 = blockIdx.x * CHUNK;
  int s1 = s0 + CHUNK;

  float a0[8] = {0,0,0,0,0,0,0,0};
  float a1[8] = {0,0,0,0,0,0,0,0};
  float a2[8] = {0,0,0,0,0,0,0,0};

#pragma unroll 2
  for (int s = s0; s < s1; ++s) {
    unsigned xr = *reinterpret_cast<const unsigned*>(xu + (size_t)s * 128 + 2 * l);
    float f0 = __uint_as_float(xr << 16);
    float f1 = __uint_as_float(xr & 0xffff0000u);
    float p  = (l < 3) ? pos[s * 3 + l] : 0.f;
    const int4* ar = reinterpret_cast<const int4*>(ai + (size_t)s * 32 + cw);
    int4 A0 = ar[0], A1 = ar[1];
    float af[8] = {(float)A0.x, (float)A0.y, (float)A0.z, (float)A0.w,
                   (float)A1.x, (float)A1.y, (float)A1.z, (float)A1.w};
#pragma unroll
    for (int cc = 0; cc < 8; ++cc) {
      a0[cc] += af[cc] * f0;
      a1[cc] += af[cc] * f1;
      a2[cc] += af[cc] * p;
    }
  }

  const float SC = 1.0f / FXSCALE;
  float* pb = partial + (size_t)blockIdx.x * MROW;
#pragma unroll
  for (int cc = 0; cc < 8; ++cc) {
    pb[(cw + cc) * ADIM + 2 * l]     = a0[cc] * SC;
    pb[(cw + cc) * ADIM + 2 * l + 1] = a1[cc] * SC;
    if (l < 3) pb[(cw + cc) * ADIM + 128 + l] = a2[cc] * SC;
  }
}

// ---------------- reduce: one wave per idx, shfl tree ----------------
__global__ __launch_bounds__(256) void reduce_kernel(const float* __restrict__ partial,
                                                     float* __restrict__ Macc) {
  int w = threadIdx.x >> 6, l = threadIdx.x & 63;
  int idx = blockIdx.x * 4 + w;
  if (idx >= MROW) return;
  float s = 0.f;
#pragma unroll
  for (int b = 0; b < NBLK; b += 64)
    s += partial[(size_t)(b + l) * MROW + idx];
  s += __shfl_xor(s, 32);
  s += __shfl_xor(s, 16);
  s += __shfl_xor(s, 8);
  s += __shfl_xor(s, 4);
  s += __shfl_xor(s, 2);
  s += __shfl_xor(s, 1);
  if (l == 0) Macc[idx] = s;
}

// ---------------- tail MLP: 1 block/cloud, 1024 threads, float4-batched deep k-split ----
__global__ __launch_bounds__(1024) void final_kernel(
    const float* __restrict__ Macc, const float* __restrict__ pos,
    const float* __restrict__ locT, const float* __restrict__ loc_b,
    const float* __restrict__ globT, const float* __restrict__ glob_b,
    const float* __restrict__ d1T, const float* __restrict__ d1b,
    const float* __restrict__ d2T, const float* __restrict__ d2b,
    const float* __restrict__ d3T, const float* __restrict__ d3b,
    float* __restrict__ out) {
  int c = blockIdx.x, t = threadIdx.x;
  int wv = t >> 6, ln = t & 63;

  __shared__ float sw[16][3];
  __shared__ float possum[3];
  __shared__ float msh[144];
  __shared__ float ttsh[256];
  __shared__ float ush[384];
  __shared__ float ash[256];
  __shared__ float bvsh[128];
  __shared__ float ptl2[4352];   // k-split partial scratch (padded layouts)

  // --- pos sum ---
  {
    const float* pr = pos + ((size_t)c * PTSC + t) * 3;
    float s0 = pr[0], s1 = pr[1], s2 = pr[2];
#pragma unroll
    for (int m_ = 32; m_ > 0; m_ >>= 1) {
      s0 += __shfl_xor(s0, m_);
      s1 += __shfl_xor(s1, m_);
      s2 += __shfl_xor(s2, m_);
    }
    if (ln == 0) { sw[wv][0] = s0; sw[wv][1] = s1; sw[wv][2] = s2; }
  }
  __syncthreads();
  if (t < 48) {
    int d = t >> 4, idx = t & 15;
    float v = sw[idx][d];
#pragma unroll
    for (int m_ = 8; m_ > 0; m_ >>= 1) v += __shfl_xor(v, m_);
    if (idx == 0) possum[d] = v;
  }
  __syncthreads();

  if (t < 128)       msh[t] = Macc[c * ADIM + t] * (1.0f / (float)PTSC);
  else if (t < 131)  msh[t] = (Macc[c * ADIM + t] - possum[t - 128]) * (1.0f / (float)PTSC);
  else if (t < 144)  msh[t] = 0.f;   // pad rows (weights read from globT region, x0)
  __syncthreads();

  // --- loc: O=256, K=144(pad), ksplit=16 (p=wave), og=lane, 9 batched float4 loads ---
  {
    int p = wv, og = ln;
    float4 wvv[9];
#pragma unroll
    for (int j = 0; j < 9; ++j) {
      int k = p * 9 + j;
      wvv[j] = *reinterpret_cast<const float4*>(locT + (size_t)k * 256 + og * 4);
    }
    float a0, a1, a2, a3;
    if (p == 0) {
      float4 b = *reinterpret_cast<const float4*>(loc_b + og * 4);
      a0 = b.x; a1 = b.y; a2 = b.z; a3 = b.w;
    } else { a0 = a1 = a2 = a3 = 0.f; }
#pragma unroll
    for (int j = 0; j < 9; ++j) {
      float x = msh[p * 9 + j];
      a0 += wvv[j].x * x; a1 += wvv[j].y * x; a2 += wvv[j].z * x; a3 += wvv[j].w * x;
    }
    ptl2[(p * 4 + 0) * 66 + og] = a0;
    ptl2[(p * 4 + 1) * 66 + og] = a1;
    ptl2[(p * 4 + 2) * 66 + og] = a2;
    ptl2[(p * 4 + 3) * 66 + og] = a3;
  }
  __syncthreads();
  if (t < 256) {
    int og = t >> 2, sub = t & 3;
    float s = 0.f;
#pragma unroll
    for (int p = 0; p < 16; ++p) s += ptl2[(p * 4 + sub) * 66 + og];
    ttsh[t] = s;
  }
  __syncthreads();

  // --- glob: O=384, K=256, ksplit=8, og=0..95, 4 batches of 8 float4 loads ---
  if (t < 768) {
    int p = t / 96, og = t - p * 96;
    float a0, a1, a2, a3;
    if (p == 0) {
      float4 b = *reinterpret_cast<const float4*>(glob_b + og * 4);
      a0 = b.x; a1 = b.y; a2 = b.z; a3 = b.w;
    } else { a0 = a1 = a2 = a3 = 0.f; }
#pragma unroll
    for (int B = 0; B < 4; ++B) {
      float4 wvv[8];
#pragma unroll
      for (int j = 0; j < 8; ++j) {
        int k = p * 32 + B * 8 + j;
        wvv[j] = *reinterpret_cast<const float4*>(globT + (size_t)k * 384 + og * 4);
      }
#pragma unroll
      for (int j = 0; j < 8; ++j) {
        float x = ttsh[p * 32 + B * 8 + j];
        a0 += wvv[j].x * x; a1 += wvv[j].y * x; a2 += wvv[j].z * x; a3 += wvv[j].w * x;
      }
    }
    ptl2[(p * 4 + 0) * 98 + og] = a0;
    ptl2[(p * 4 + 1) * 98 + og] = a1;
    ptl2[(p * 4 + 2) * 98 + og] = a2;
    ptl2[(p * 4 + 3) * 98 + og] = a3;
  }
  __syncthreads();
  if (t < 384) {
    int og = t >> 2, sub = t & 3;
    float s = 0.f;
#pragma unroll
    for (int p = 0; p < 8; ++p) s += ptl2[(p * 4 + sub) * 98 + og];
    ush[t] = s;
  }
  __syncthreads();

  // --- d1: O=256, K=384, ksplit=16, 3 batches of 8 float4 loads, tanh ---
  {
    int p = wv, og = ln;
    float a0, a1, a2, a3;
    if (p == 0) {
      float4 b = *reinterpret_cast<const float4*>(d1b + og * 4);
      a0 = b.x; a1 = b.y; a2 = b.z; a3 = b.w;
    } else { a0 = a1 = a2 = a3 = 0.f; }
#pragma unroll
    for (int B = 0; B < 3; ++B) {
      float4 wvv[8];
#pragma unroll
      for (int j = 0; j < 8; ++j) {
        int k = p * 24 + B * 8 + j;
        wvv[j] = *reinterpret_cast<const float4*>(d1T + (size_t)k * 256 + og * 4);
      }
#pragma unroll
      for (int j = 0; j < 8; ++j) {
        float x = ush[p * 24 + B * 8 + j];
        a0 += wvv[j].x * x; a1 += wvv[j].y * x; a2 += wvv[j].z * x; a3 += wvv[j].w * x;
      }
    }
    ptl2[(p * 4 + 0) * 66 + og] = a0;
    ptl2[(p * 4 + 1) * 66 + og] = a1;
    ptl2[(p * 4 + 2) * 66 + og] = a2;
    ptl2[(p * 4 + 3) * 66 + og] = a3;
  }
  __syncthreads();
  if (t < 256) {
    int og = t >> 2, sub = t & 3;
    float s = 0.f;
#pragma unroll
    for (int p = 0; p < 16; ++p) s += ptl2[(p * 4 + sub) * 66 + og];
    ash[t] = tanhf(s);
  }
  __syncthreads();

  // --- d2: O=128, K=256, ksplit=32, og=0..31, 8 batched float4 loads, tanh ---
  {
    int p = t >> 5, og = t & 31;
    float4 wvv[8];
#pragma unroll
    for (int j = 0; j < 8; ++j) {
      int k = p * 8 + j;
      wvv[j] = *reinterpret_cast<const float4*>(d2T + (size_t)k * 128 + og * 4);
    }
    float a0, a1, a2, a3;
    if (p == 0) {
      float4 b = *reinterpret_cast<const float4*>(d2b + og * 4);
      a0 = b.x; a1 = b.y; a2 = b.z; a3 = b.w;
    } else { a0 = a1 = a2 = a3 = 0.f; }
#pragma unroll
    for (int j = 0; j < 8; ++j) {
      float x = ash[p * 8 + j];
      a0 += wvv[j].x * x; a1 += wvv[j].y * x; a2 += wvv[j].z * x; a3 += wvv[j].w * x;
    }
    ptl2[(p * 4 + 0) * 34 + og] = a0;
    ptl2[(p * 4 + 1) * 34 + og] = a1;
    ptl2[(p * 4 + 2) * 34 + og] = a2;
    ptl2[(p * 4 + 3) * 34 + og] = a3;
  }
  __syncthreads();
  if (t < 128) {
    int og = t >> 2, sub = t & 3;
    float s = 0.f;
#pragma unroll
    for (int p = 0; p < 32; ++p) s += ptl2[(p * 4 + sub) * 34 + og];
    bvsh[t] = tanhf(s);
  }
  __syncthreads();

  // --- d3: O=16, K=128, one wave per output ---
  {
    int o = wv, k = ln;
    float acc = d3T[k * 16 + o] * bvsh[k] + d3T[(k + 64) * 16 + o] * bvsh[k + 64];
#pragma unroll
    for (int m_ = 32; m_ > 0; m_ >>= 1) acc += __shfl_xor(acc, m_);
    if (ln == 0) out[c * 16 + o] = acc + d3b[o];
  }
}

extern "C" void kernel_launch(void* const* d_in, const int* in_sizes, int n_in,
                              void* d_out, int out_size, void* d_ws, size_t ws_size,
                              hipStream_t stream) {
  const float* pos    = (const float*)d_in[0];
  const int*   ei     = (const int*)d_in[1];
  const float* enc1_w = (const float*)d_in[2];
  const float* enc1_b = (const float*)d_in[3];
  const float* enc2_w = (const float*)d_in[4];
  const float* enc2_b = (const float*)d_in[5];
  const float* enc3_w = (const float*)d_in[6];
  const float* enc3_b = (const float*)d_in[7];
  const float* loc_w  = (const float*)d_in[8];
  const float* loc_b  = (const float*)d_in[9];
  const float* glob_w = (const float*)d_in[10];
  const float* glob_b = (const float*)d_in[11];
  const float* d1w    = (const float*)d_in[12];
  const float* d1b    = (const float*)d_in[13];
  const float* d2w    = (const float*)d_in[14];
  const float* d2b    = (const float*)d_in[15];
  const float* d3w    = (const float*)d_in[16];
  const float* d3b    = (const float*)d_in[17];
  float* out = (float*)d_out;

  // workspace layout (bytes, 256B-aligned)
  char* ws = (char*)d_ws;
  size_t o = 0;
  __hip_bfloat16* xb = (__hip_bfloat16*)(ws + o); o += 8388608;     // N*128 bf16
  int*   ai    = (int*)  (ws + o); o += 4194304;                    // N*32 i32
  int*   cnt   = (int*)  (ws + o); o += 131072;
  int*   invwi = (int*)  (ws + o); o += 131072;
  float* Macc  = (float*)(ws + o); o += 17408;                      // MROW padded
  float* w2T   = (float*)(ws + o); o += 16384;
  float* w3T   = (float*)(ws + o); o += 32768;
  float* locT  = (float*)(ws + o); o += 134144;
  float* globT = (float*)(ws + o); o += 393216;
  float* d1T   = (float*)(ws + o); o += 393216;
  float* d2T   = (float*)(ws + o); o += 131072;
  float* d3T   = (float*)(ws + o); o += 8192;
  float* partial = (float*)(ws + o);                                // NBLK*MROW f32
  (void)ws_size;

  prep_kernel<<<1211, 256, 0, stream>>>(enc2_w, enc3_w, loc_w, glob_w, d1w, d2w, d3w,
                                        w2T, w3T, locT, globT, d1T, d2T, d3T, cnt);
  hist_kernel<<<EEDGES / 1024, 256, 0, stream>>>(ei, cnt);
  invwi_kernel<<<NPTS / 256, 256, 0, stream>>>(cnt, invwi, ai);
  enc_kernel<<<NPTS / 32, 256, 0, stream>>>(pos, enc1_w, enc1_b, w2T, enc2_b,
                                            w3T, enc3_b, xb);
  ascatter_kernel<<<EEDGES / 1024, 256, 0, stream>>>(ei, invwi, ai);
  contract_kernel<<<NBLK, 256, 0, stream>>>((const ushort*)xb, pos, ai, partial);
  reduce_kernel<<<MROW / 4, 256, 0, stream>>>(partial, Macc);
  final_kernel<<<NCLOUD, 1024, 0, stream>>>(Macc, pos, locT, loc_b, globT, glob_b,
                                            d1T, d1b, d2T, d2b, d3T, d3b, out);
}

// Round 20
// 173.990 us; speedup vs baseline: 1.0383x; 1.0132x over previous
//
#include <hip/hip_runtime.h>
#include <hip/hip_bf16.h>

#define NPTS   32768
#define EEDGES 1048576
#define PTSC   1024
#define NCLOUD 32
#define ADIM   132              // per-cloud stride: 128 x + 3 pos + pad
#define MROW   (NCLOUD * ADIM)  // 4224
#define NBLK   256              // contract partial blocks
#define CHUNK  (NPTS / NBLK)    // 128
#define FXSCALE 16777216.0f     // 2^24

// ---------------- weight transpose prep + cnt zeroing ----------------
__global__ __launch_bounds__(256) void prep_kernel(
    const float* __restrict__ w2, const float* __restrict__ w3,
    const float* __restrict__ locw, const float* __restrict__ globw,
    const float* __restrict__ d1w, const float* __restrict__ d2w,
    const float* __restrict__ d3w,
    float* __restrict__ w2T, float* __restrict__ w3T,
    float* __restrict__ locT, float* __restrict__ globT,
    float* __restrict__ d1T, float* __restrict__ d2T, float* __restrict__ d3T,
    int* __restrict__ cnt) {
  int idx = blockIdx.x * 256 + threadIdx.x;
  if (idx >= 277248) {
    cnt[idx - 277248] = 0;
    return;
  }
  const float* src; float* dst; int R, C;
  if (idx < 4096)        { src = w2;   dst = w2T;   R = 64;  C = 64;  }
  else if (idx < 12288)  { src = w3;   dst = w3T;   R = 128; C = 64;  idx -= 4096; }
  else if (idx < 45824)  { src = locw; dst = locT;  R = 256; C = 131; idx -= 12288; }
  else if (idx < 144128) { src = globw;dst = globT; R = 384; C = 256; idx -= 45824; }
  else if (idx < 242432) { src = d1w;  dst = d1T;   R = 256; C = 384; idx -= 144128; }
  else if (idx < 275200) { src = d2w;  dst = d2T;   R = 128; C = 256; idx -= 242432; }
  else                   { src = d3w;  dst = d3T;   R = 16;  C = 128; idx -= 275200; }
  int c = idx / R, r = idx % R;
  dst[idx] = src[r * C + c];
}

__device__ __forceinline__ unsigned pack_bf16(float a, float b) {
  __hip_bfloat162 o;
  o.x = __float2bfloat16(a);
  o.y = __float2bfloat16(b);
  return *reinterpret_cast<unsigned*>(&o);
}

__device__ __forceinline__ float rlane(float x, int k) {
  return __int_as_float(__builtin_amdgcn_readlane(__float_as_int(x), k));
}

// fast tanh: 1 - 2/(exp(2x)+1)
__device__ __forceinline__ float fast_tanh(float x) {
  float e = __expf(2.0f * x);
  return 1.0f - 2.0f * __builtin_amdgcn_rcpf(e + 1.0f);
}

// ---------------- degree histogram ----------------
__global__ __launch_bounds__(256) void hist_kernel(const int* __restrict__ ei,
                                                   int* __restrict__ cnt) {
  int t = blockIdx.x * 256 + threadIdx.x;
  const int4* d4 = reinterpret_cast<const int4*>(ei + EEDGES);
  int4 v = d4[t];
  atomicAdd(&cnt[v.x], 1);
  atomicAdd(&cnt[v.y], 1);
  atomicAdd(&cnt[v.z], 1);
  atomicAdd(&cnt[v.w], 1);
}

// invwi + full alpha-row init (zeros + self-loop diagonal)
__global__ __launch_bounds__(256) void invwi_kernel(const int* __restrict__ cnt,
                                                    int* __restrict__ invwi,
                                                    int* __restrict__ ai) {
  int i = blockIdx.x * 256 + threadIdx.x;
  int v = (int)rintf(FXSCALE / (float)(cnt[i] + 1));
  invwi[i] = v;
  int4 z = make_int4(0, 0, 0, 0);
  int4* row = reinterpret_cast<int4*>(ai + i * 32);
#pragma unroll
  for (int q = 0; q < 8; ++q) row[q] = z;
  ai[i * 32 + (i >> 10)] = v;   // self-loop contribution
}

// ---------------- FUSED: ascatter (blocks 0..1023) + encoder (blocks 1024..2047) ----
// independent work on disjoint pipes (atomic vs VALU) — overlap in one dispatch.
__global__ __launch_bounds__(256) void enc_ascatter_kernel(
    const int* __restrict__ ei, const int* __restrict__ invwi, int* __restrict__ ai,
    const float* __restrict__ pos,
    const float* __restrict__ w1, const float* __restrict__ b1,
    const float* __restrict__ w2T, const float* __restrict__ b2,
    const float* __restrict__ w3T, const float* __restrict__ b3,
    __hip_bfloat16* __restrict__ xb) {
  if (blockIdx.x < EEDGES / 1024) {
    // ---- ascatter: 4 edges/thread ----
    int t = blockIdx.x * 256 + threadIdx.x;
    const int4* s4 = reinterpret_cast<const int4*>(ei);
    const int4* d4 = reinterpret_cast<const int4*>(ei + EEDGES);
    int4 s = s4[t];
    int4 d = d4[t];
    int w0 = invwi[d.x];
    int w1i = invwi[d.y];
    int w2i = invwi[d.z];
    int w3i = invwi[d.w];
    atomicAdd(&ai[s.x * 32 + (d.x >> 10)], w0);
    atomicAdd(&ai[s.y * 32 + (d.y >> 10)], w1i);
    atomicAdd(&ai[s.z * 32 + (d.z >> 10)], w2i);
    atomicAdd(&ai[s.w * 32 + (d.w >> 10)], w3i);
    return;
  }
  // ---- encoder: 8 pts/wave ----
  int wid  = ((blockIdx.x - EEDGES / 1024) * 256 + threadIdx.x) >> 6;
  int lane = threadIdx.x & 63;
  int i0 = __builtin_amdgcn_readfirstlane(wid * 8);

  float w1a = w1[lane * 3 + 0], w1b = w1[lane * 3 + 1], w1c = w1[lane * 3 + 2];
  float bb1 = b1[lane];

  float h1[8];
#pragma unroll
  for (int p = 0; p < 8; ++p) {
    int i = i0 + p;
    float px = pos[i * 3 + 0], py = pos[i * 3 + 1], pz = pos[i * 3 + 2];
    h1[p] = fast_tanh(w1a * px + w1b * py + w1c * pz + bb1);
  }

  float bb2 = b2[lane];
  float acc2[8];
#pragma unroll
  for (int p = 0; p < 8; ++p) acc2[p] = bb2;
#pragma unroll
  for (int k = 0; k < 64; ++k) {
    float w = w2T[k * 64 + lane];
#pragma unroll
    for (int p = 0; p < 8; ++p) acc2[p] += w * rlane(h1[p], k);
  }
  float h2[8];
#pragma unroll
  for (int p = 0; p < 8; ++p) h2[p] = fast_tanh(acc2[p]);

  int r0 = 2 * lane;
  float bb3a = b3[r0], bb3b = b3[r0 + 1];
  float acc3a[8], acc3b[8];
#pragma unroll
  for (int p = 0; p < 8; ++p) { acc3a[p] = bb3a; acc3b[p] = bb3b; }
#pragma unroll
  for (int k = 0; k < 64; ++k) {
    float2 w = *reinterpret_cast<const float2*>(w3T + k * 128 + r0);
#pragma unroll
    for (int p = 0; p < 8; ++p) {
      float h = rlane(h2[p], k);
      acc3a[p] += w.x * h;
      acc3b[p] += w.y * h;
    }
  }
#pragma unroll
  for (int p = 0; p < 8; ++p) {
    int i = i0 + p;
    unsigned o = pack_bf16(fast_tanh(acc3a[p]), fast_tanh(acc3b[p]));
    *reinterpret_cast<unsigned*>(xb + (size_t)i * 128 + r0) = o;
  }
}

// ---------------- contraction ----------------
__global__ __launch_bounds__(256) void contract_kernel(
    const ushort* __restrict__ xu, const float* __restrict__ pos,
    const int* __restrict__ ai, float* __restrict__ partial) {
  int w = threadIdx.x >> 6, l = threadIdx.x & 63;
  int cw = w * 8;
  int s0 = blockIdx.x * CHUNK;
  int s1 = s0 + CHUNK;

  float a0[8] = {0,0,0,0,0,0,0,0};
  float a1[8] = {0,0,0,0,0,0,0,0};
  float a2[8] = {0,0,0,0,0,0,0,0};

#pragma unroll 2
  for (int s = s0; s < s1; ++s) {
    unsigned xr = *reinterpret_cast<const unsigned*>(xu + (size_t)s * 128 + 2 * l);
    float f0 = __uint_as_float(xr << 16);
    float f1 = __uint_as_float(xr & 0xffff0000u);
    float p  = (l < 3) ? pos[s * 3 + l] : 0.f;
    const int4* ar = reinterpret_cast<const int4*>(ai + (size_t)s * 32 + cw);
    int4 A0 = ar[0], A1 = ar[1];
    float af[8] = {(float)A0.x, (float)A0.y, (float)A0.z, (float)A0.w,
                   (float)A1.x, (float)A1.y, (float)A1.z, (float)A1.w};
#pragma unroll
    for (int cc = 0; cc < 8; ++cc) {
      a0[cc] += af[cc] * f0;
      a1[cc] += af[cc] * f1;
      a2[cc] += af[cc] * p;
    }
  }

  const float SC = 1.0f / FXSCALE;
  float* pb = partial + (size_t)blockIdx.x * MROW;
#pragma unroll
  for (int cc = 0; cc < 8; ++cc) {
    pb[(cw + cc) * ADIM + 2 * l]     = a0[cc] * SC;
    pb[(cw + cc) * ADIM + 2 * l + 1] = a1[cc] * SC;
    if (l < 3) pb[(cw + cc) * ADIM + 128 + l] = a2[cc] * SC;
  }
}

// ---------------- reduce ----------------
__global__ __launch_bounds__(256) void reduce_kernel(const float* __restrict__ partial,
                                                     float* __restrict__ Macc) {
  int w = threadIdx.x >> 6, l = threadIdx.x & 63;
  int idx = blockIdx.x * 4 + w;
  if (idx >= MROW) return;
  float s = 0.f;
#pragma unroll
  for (int b = 0; b < NBLK; b += 64)
    s += partial[(size_t)(b + l) * MROW + idx];
  s += __shfl_xor(s, 32);
  s += __shfl_xor(s, 16);
  s += __shfl_xor(s, 8);
  s += __shfl_xor(s, 4);
  s += __shfl_xor(s, 2);
  s += __shfl_xor(s, 1);
  if (l == 0) Macc[idx] = s;
}

// ---------------- tail MLP ----------------
__global__ __launch_bounds__(1024) void final_kernel(
    const float* __restrict__ Macc, const float* __restrict__ pos,
    const float* __restrict__ locT, const float* __restrict__ loc_b,
    const float* __restrict__ globT, const float* __restrict__ glob_b,
    const float* __restrict__ d1T, const float* __restrict__ d1b,
    const float* __restrict__ d2T, const float* __restrict__ d2b,
    const float* __restrict__ d3T, const float* __restrict__ d3b,
    float* __restrict__ out) {
  int c = blockIdx.x, t = threadIdx.x;
  int wv = t >> 6, ln = t & 63;

  __shared__ float sw[16][3];
  __shared__ float possum[3];
  __shared__ float msh[144];
  __shared__ float ttsh[256];
  __shared__ float ush[384];
  __shared__ float ash[256];
  __shared__ float bvsh[128];
  __shared__ float ptl2[4352];

  {
    const float* pr = pos + ((size_t)c * PTSC + t) * 3;
    float s0 = pr[0], s1 = pr[1], s2 = pr[2];
#pragma unroll
    for (int m_ = 32; m_ > 0; m_ >>= 1) {
      s0 += __shfl_xor(s0, m_);
      s1 += __shfl_xor(s1, m_);
      s2 += __shfl_xor(s2, m_);
    }
    if (ln == 0) { sw[wv][0] = s0; sw[wv][1] = s1; sw[wv][2] = s2; }
  }
  __syncthreads();
  if (t < 48) {
    int d = t >> 4, idx = t & 15;
    float v = sw[idx][d];
#pragma unroll
    for (int m_ = 8; m_ > 0; m_ >>= 1) v += __shfl_xor(v, m_);
    if (idx == 0) possum[d] = v;
  }
  __syncthreads();

  if (t < 128)       msh[t] = Macc[c * ADIM + t] * (1.0f / (float)PTSC);
  else if (t < 131)  msh[t] = (Macc[c * ADIM + t] - possum[t - 128]) * (1.0f / (float)PTSC);
  else if (t < 144)  msh[t] = 0.f;
  __syncthreads();

  {
    int p = wv, og = ln;
    float4 wvv[9];
#pragma unroll
    for (int j = 0; j < 9; ++j) {
      int k = p * 9 + j;
      wvv[j] = *reinterpret_cast<const float4*>(locT + (size_t)k * 256 + og * 4);
    }
    float a0, a1, a2, a3;
    if (p == 0) {
      float4 b = *reinterpret_cast<const float4*>(loc_b + og * 4);
      a0 = b.x; a1 = b.y; a2 = b.z; a3 = b.w;
    } else { a0 = a1 = a2 = a3 = 0.f; }
#pragma unroll
    for (int j = 0; j < 9; ++j) {
      float x = msh[p * 9 + j];
      a0 += wvv[j].x * x; a1 += wvv[j].y * x; a2 += wvv[j].z * x; a3 += wvv[j].w * x;
    }
    ptl2[(p * 4 + 0) * 66 + og] = a0;
    ptl2[(p * 4 + 1) * 66 + og] = a1;
    ptl2[(p * 4 + 2) * 66 + og] = a2;
    ptl2[(p * 4 + 3) * 66 + og] = a3;
  }
  __syncthreads();
  if (t < 256) {
    int og = t >> 2, sub = t & 3;
    float s = 0.f;
#pragma unroll
    for (int p = 0; p < 16; ++p) s += ptl2[(p * 4 + sub) * 66 + og];
    ttsh[t] = s;
  }
  __syncthreads();

  if (t < 768) {
    int p = t / 96, og = t - p * 96;
    float a0, a1, a2, a3;
    if (p == 0) {
      float4 b = *reinterpret_cast<const float4*>(glob_b + og * 4);
      a0 = b.x; a1 = b.y; a2 = b.z; a3 = b.w;
    } else { a0 = a1 = a2 = a3 = 0.f; }
#pragma unroll
    for (int B = 0; B < 4; ++B) {
      float4 wvv[8];
#pragma unroll
      for (int j = 0; j < 8; ++j) {
        int k = p * 32 + B * 8 + j;
        wvv[j] = *reinterpret_cast<const float4*>(globT + (size_t)k * 384 + og * 4);
      }
#pragma unroll
      for (int j = 0; j < 8; ++j) {
        float x = ttsh[p * 32 + B * 8 + j];
        a0 += wvv[j].x * x; a1 += wvv[j].y * x; a2 += wvv[j].z * x; a3 += wvv[j].w * x;
      }
    }
    ptl2[(p * 4 + 0) * 98 + og] = a0;
    ptl2[(p * 4 + 1) * 98 + og] = a1;
    ptl2[(p * 4 + 2) * 98 + og] = a2;
    ptl2[(p * 4 + 3) * 98 + og] = a3;
  }
  __syncthreads();
  if (t < 384) {
    int og = t >> 2, sub = t & 3;
    float s = 0.f;
#pragma unroll
    for (int p = 0; p < 8; ++p) s += ptl2[(p * 4 + sub) * 98 + og];
    ush[t] = s;
  }
  __syncthreads();

  {
    int p = wv, og = ln;
    float a0, a1, a2, a3;
    if (p == 0) {
      float4 b = *reinterpret_cast<const float4*>(d1b + og * 4);
      a0 = b.x; a1 = b.y; a2 = b.z; a3 = b.w;
    } else { a0 = a1 = a2 = a3 = 0.f; }
#pragma unroll
    for (int B = 0; B < 3; ++B) {
      float4 wvv[8];
#pragma unroll
      for (int j = 0; j < 8; ++j) {
        int k = p * 24 + B * 8 + j;
        wvv[j] = *reinterpret_cast<const float4*>(d1T + (size_t)k * 256 + og * 4);
      }
#pragma unroll
      for (int j = 0; j < 8; ++j) {
        float x = ush[p * 24 + B * 8 + j];
        a0 += wvv[j].x * x; a1 += wvv[j].y * x; a2 += wvv[j].z * x; a3 += wvv[j].w * x;
      }
    }
    ptl2[(p * 4 + 0) * 66 + og] = a0;
    ptl2[(p * 4 + 1) * 66 + og] = a1;
    ptl2[(p * 4 + 2) * 66 + og] = a2;
    ptl2[(p * 4 + 3) * 66 + og] = a3;
  }
  __syncthreads();
  if (t < 256) {
    int og = t >> 2, sub = t & 3;
    float s = 0.f;
#pragma unroll
    for (int p = 0; p < 16; ++p) s += ptl2[(p * 4 + sub) * 66 + og];
    ash[t] = tanhf(s);
  }
  __syncthreads();

  {
    int p = t >> 5, og = t & 31;
    float4 wvv[8];
#pragma unroll
    for (int j = 0; j < 8; ++j) {
      int k = p * 8 + j;
      wvv[j] = *reinterpret_cast<const float4*>(d2T + (size_t)k * 128 + og * 4);
    }
    float a0, a1, a2, a3;
    if (p == 0) {
      float4 b = *reinterpret_cast<const float4*>(d2b + og * 4);
      a0 = b.x; a1 = b.y; a2 = b.z; a3 = b.w;
    } else { a0 = a1 = a2 = a3 = 0.f; }
#pragma unroll
    for (int j = 0; j < 8; ++j) {
      float x = ash[p * 8 + j];
      a0 += wvv[j].x * x; a1 += wvv[j].y * x; a2 += wvv[j].z * x; a3 += wvv[j].w * x;
    }
    ptl2[(p * 4 + 0) * 34 + og] = a0;
    ptl2[(p * 4 + 1) * 34 + og] = a1;
    ptl2[(p * 4 + 2) * 34 + og] = a2;
    ptl2[(p * 4 + 3) * 34 + og] = a3;
  }
  __syncthreads();
  if (t < 128) {
    int og = t >> 2, sub = t & 3;
    float s = 0.f;
#pragma unroll
    for (int p = 0; p < 32; ++p) s += ptl2[(p * 4 + sub) * 34 + og];
    bvsh[t] = tanhf(s);
  }
  __syncthreads();

  {
    int o = wv, k = ln;
    float acc = d3T[k * 16 + o] * bvsh[k] + d3T[(k + 64) * 16 + o] * bvsh[k + 64];
#pragma unroll
    for (int m_ = 32; m_ > 0; m_ >>= 1) acc += __shfl_xor(acc, m_);
    if (ln == 0) out[c * 16 + o] = acc + d3b[o];
  }
}

extern "C" void kernel_launch(void* const* d_in, const int* in_sizes, int n_in,
                              void* d_out, int out_size, void* d_ws, size_t ws_size,
                              hipStream_t stream) {
  const float* pos    = (const float*)d_in[0];
  const int*   ei     = (const int*)d_in[1];
  const float* enc1_w = (const float*)d_in[2];
  const float* enc1_b = (const float*)d_in[3];
  const float* enc2_w = (const float*)d_in[4];
  const float* enc2_b = (const float*)d_in[5];
  const float* enc3_w = (const float*)d_in[6];
  const float* enc3_b = (const float*)d_in[7];
  const float* loc_w  = (const float*)d_in[8];
  const float* loc_b  = (const float*)d_in[9];
  const float* glob_w = (const float*)d_in[10];
  const float* glob_b = (const float*)d_in[11];
  const float* d1w    = (const float*)d_in[12];
  const float* d1b    = (const float*)d_in[13];
  const float* d2w    = (const float*)d_in[14];
  const float* d2b    = (const float*)d_in[15];
  const float* d3w    = (const float*)d_in[16];
  const float* d3b    = (const float*)d_in[17];
  float* out = (float*)d_out;

  // workspace layout (bytes, 256B-aligned)
  char* ws = (char*)d_ws;
  size_t o = 0;
  __hip_bfloat16* xb = (__hip_bfloat16*)(ws + o); o += 8388608;     // N*128 bf16
  int*   ai    = (int*)  (ws + o); o += 4194304;                    // N*32 i32
  int*   cnt   = (int*)  (ws + o); o += 131072;
  int*   invwi = (int*)  (ws + o); o += 131072;
  float* Macc  = (float*)(ws + o); o += 17408;                      // MROW padded
  float* w2T   = (float*)(ws + o); o += 16384;
  float* w3T   = (float*)(ws + o); o += 32768;
  float* locT  = (float*)(ws + o); o += 134144;
  float* globT = (float*)(ws + o); o += 393216;
  float* d1T   = (float*)(ws + o); o += 393216;
  float* d2T   = (float*)(ws + o); o += 131072;
  float* d3T   = (float*)(ws + o); o += 8192;
  float* partial = (float*)(ws + o);                                // NBLK*MROW f32
  (void)ws_size;

  prep_kernel<<<1211, 256, 0, stream>>>(enc2_w, enc3_w, loc_w, glob_w, d1w, d2w, d3w,
                                        w2T, w3T, locT, globT, d1T, d2T, d3T, cnt);
  hist_kernel<<<EEDGES / 1024, 256, 0, stream>>>(ei, cnt);
  invwi_kernel<<<NPTS / 256, 256, 0, stream>>>(cnt, invwi, ai);
  enc_ascatter_kernel<<<EEDGES / 1024 + NPTS / 32, 256, 0, stream>>>(
      ei, invwi, ai, pos, enc1_w, enc1_b, w2T, enc2_b, w3T, enc3_b, xb);
  contract_kernel<<<NBLK, 256, 0, stream>>>((const ushort*)xb, pos, ai, partial);
  reduce_kernel<<<MROW / 4, 256, 0, stream>>>(partial, Macc);
  final_kernel<<<NCLOUD, 1024, 0, stream>>>(Macc, pos, locT, loc_b, globT, glob_b,
                                            d1T, d1b, d2T, d2b, d3T, d3b, out);
}

// Round 22
// 170.179 us; speedup vs baseline: 1.0615x; 1.0224x over previous
//
#include <hip/hip_runtime.h>
#include <hip/hip_bf16.h>

#define NPTS   32768
#define EEDGES 1048576
#define PTSC   1024
#define NCLOUD 32
#define ADIM   132              // per-cloud stride: 128 x + 3 pos + pad
#define MROW   (NCLOUD * ADIM)  // 4224
#define NBLK   256              // contract partial blocks
#define CHUNK  (NPTS / NBLK)    // 128
#define FXSCALE 16777216.0f     // 2^24

// ---------------- weight transpose prep + cnt zeroing ----------------
__global__ __launch_bounds__(256) void prep_kernel(
    const float* __restrict__ w2, const float* __restrict__ w3,
    const float* __restrict__ locw, const float* __restrict__ globw,
    const float* __restrict__ d1w, const float* __restrict__ d2w,
    const float* __restrict__ d3w,
    float* __restrict__ w2T, float* __restrict__ w3T,
    float* __restrict__ locT, float* __restrict__ globT,
    float* __restrict__ d1T, float* __restrict__ d2T, float* __restrict__ d3T,
    int* __restrict__ cnt) {
  int idx = blockIdx.x * 256 + threadIdx.x;
  if (idx >= 277248) {
    cnt[idx - 277248] = 0;
    return;
  }
  const float* src; float* dst; int R, C;
  if (idx < 4096)        { src = w2;   dst = w2T;   R = 64;  C = 64;  }
  else if (idx < 12288)  { src = w3;   dst = w3T;   R = 128; C = 64;  idx -= 4096; }
  else if (idx < 45824)  { src = locw; dst = locT;  R = 256; C = 131; idx -= 12288; }
  else if (idx < 144128) { src = globw;dst = globT; R = 384; C = 256; idx -= 45824; }
  else if (idx < 242432) { src = d1w;  dst = d1T;   R = 256; C = 384; idx -= 144128; }
  else if (idx < 275200) { src = d2w;  dst = d2T;   R = 128; C = 256; idx -= 242432; }
  else                   { src = d3w;  dst = d3T;   R = 16;  C = 128; idx -= 275200; }
  int c = idx / R, r = idx % R;
  dst[idx] = src[r * C + c];
}

__device__ __forceinline__ unsigned pack_bf16(float a, float b) {
  __hip_bfloat162 o;
  o.x = __float2bfloat16(a);
  o.y = __float2bfloat16(b);
  return *reinterpret_cast<unsigned*>(&o);
}

__device__ __forceinline__ float rlane(float x, int k) {
  return __int_as_float(__builtin_amdgcn_readlane(__float_as_int(x), k));
}

// fast tanh: 1 - 2/(exp(2x)+1)
__device__ __forceinline__ float fast_tanh(float x) {
  float e = __expf(2.0f * x);
  return 1.0f - 2.0f * __builtin_amdgcn_rcpf(e + 1.0f);
}

// ---------------- degree histogram ----------------
__global__ __launch_bounds__(256) void hist_kernel(const int* __restrict__ ei,
                                                   int* __restrict__ cnt) {
  int t = blockIdx.x * 256 + threadIdx.x;
  const int4* d4 = reinterpret_cast<const int4*>(ei + EEDGES);
  int4 v = d4[t];
  atomicAdd(&cnt[v.x], 1);
  atomicAdd(&cnt[v.y], 1);
  atomicAdd(&cnt[v.z], 1);
  atomicAdd(&cnt[v.w], 1);
}

// invwi + full alpha-row init (zeros + self-loop diagonal)
__global__ __launch_bounds__(256) void invwi_kernel(const int* __restrict__ cnt,
                                                    int* __restrict__ invwi,
                                                    int* __restrict__ ai) {
  int i = blockIdx.x * 256 + threadIdx.x;
  int v = (int)rintf(FXSCALE / (float)(cnt[i] + 1));
  invwi[i] = v;
  int4 z = make_int4(0, 0, 0, 0);
  int4* row = reinterpret_cast<int4*>(ai + i * 32);
#pragma unroll
  for (int q = 0; q < 8; ++q) row[q] = z;
  ai[i * 32 + (i >> 10)] = v;   // self-loop contribution
}

// ---------------- FUSED: ascatter (blocks 0..1023) + encoder (blocks 1024..2047) ----
__global__ __launch_bounds__(256) void enc_ascatter_kernel(
    const int* __restrict__ ei, const int* __restrict__ invwi, int* __restrict__ ai,
    const float* __restrict__ pos,
    const float* __restrict__ w1, const float* __restrict__ b1,
    const float* __restrict__ w2T, const float* __restrict__ b2,
    const float* __restrict__ w3T, const float* __restrict__ b3,
    __hip_bfloat16* __restrict__ xb) {
  if (blockIdx.x < EEDGES / 1024) {
    int t = blockIdx.x * 256 + threadIdx.x;
    const int4* s4 = reinterpret_cast<const int4*>(ei);
    const int4* d4 = reinterpret_cast<const int4*>(ei + EEDGES);
    int4 s = s4[t];
    int4 d = d4[t];
    int w0 = invwi[d.x];
    int w1i = invwi[d.y];
    int w2i = invwi[d.z];
    int w3i = invwi[d.w];
    atomicAdd(&ai[s.x * 32 + (d.x >> 10)], w0);
    atomicAdd(&ai[s.y * 32 + (d.y >> 10)], w1i);
    atomicAdd(&ai[s.z * 32 + (d.z >> 10)], w2i);
    atomicAdd(&ai[s.w * 32 + (d.w >> 10)], w3i);
    return;
  }
  int wid  = ((blockIdx.x - EEDGES / 1024) * 256 + threadIdx.x) >> 6;
  int lane = threadIdx.x & 63;
  int i0 = __builtin_amdgcn_readfirstlane(wid * 8);

  float w1a = w1[lane * 3 + 0], w1b = w1[lane * 3 + 1], w1c = w1[lane * 3 + 2];
  float bb1 = b1[lane];

  float h1[8];
#pragma unroll
  for (int p = 0; p < 8; ++p) {
    int i = i0 + p;
    float px = pos[i * 3 + 0], py = pos[i * 3 + 1], pz = pos[i * 3 + 2];
    h1[p] = fast_tanh(w1a * px + w1b * py + w1c * pz + bb1);
  }

  float bb2 = b2[lane];
  float acc2[8];
#pragma unroll
  for (int p = 0; p < 8; ++p) acc2[p] = bb2;
#pragma unroll
  for (int k = 0; k < 64; ++k) {
    float w = w2T[k * 64 + lane];
#pragma unroll
    for (int p = 0; p < 8; ++p) acc2[p] += w * rlane(h1[p], k);
  }
  float h2[8];
#pragma unroll
  for (int p = 0; p < 8; ++p) h2[p] = fast_tanh(acc2[p]);

  int r0 = 2 * lane;
  float bb3a = b3[r0], bb3b = b3[r0 + 1];
  float acc3a[8], acc3b[8];
#pragma unroll
  for (int p = 0; p < 8; ++p) { acc3a[p] = bb3a; acc3b[p] = bb3b; }
#pragma unroll
  for (int k = 0; k < 64; ++k) {
    float2 w = *reinterpret_cast<const float2*>(w3T + k * 128 + r0);
#pragma unroll
    for (int p = 0; p < 8; ++p) {
      float h = rlane(h2[p], k);
      acc3a[p] += w.x * h;
      acc3b[p] += w.y * h;
    }
  }
#pragma unroll
  for (int p = 0; p < 8; ++p) {
    int i = i0 + p;
    unsigned o = pack_bf16(fast_tanh(acc3a[p]), fast_tanh(acc3b[p]));
    *reinterpret_cast<unsigned*>(xb + (size_t)i * 128 + r0) = o;
  }
}

// ---------------- contraction ----------------
__global__ __launch_bounds__(256) void contract_kernel(
    const ushort* __restrict__ xu, const float* __restrict__ pos,
    const int* __restrict__ ai, float* __restrict__ partial) {
  int w = threadIdx.x >> 6, l = threadIdx.x & 63;
  int cw = w * 8;
  int s0 = blockIdx.x * CHUNK;
  int s1 = s0 + CHUNK;

  float a0[8] = {0,0,0,0,0,0,0,0};
  float a1[8] = {0,0,0,0,0,0,0,0};
  float a2[8] = {0,0,0,0,0,0,0,0};

#pragma unroll 2
  for (int s = s0; s < s1; ++s) {
    unsigned xr = *reinterpret_cast<const unsigned*>(xu + (size_t)s * 128 + 2 * l);
    float f0 = __uint_as_float(xr << 16);
    float f1 = __uint_as_float(xr & 0xffff0000u);
    float p  = (l < 3) ? pos[s * 3 + l] : 0.f;
    const int4* ar = reinterpret_cast<const int4*>(ai + (size_t)s * 32 + cw);
    int4 A0 = ar[0], A1 = ar[1];
    float af[8] = {(float)A0.x, (float)A0.y, (float)A0.z, (float)A0.w,
                   (float)A1.x, (float)A1.y, (float)A1.z, (float)A1.w};
#pragma unroll
    for (int cc = 0; cc < 8; ++cc) {
      a0[cc] += af[cc] * f0;
      a1[cc] += af[cc] * f1;
      a2[cc] += af[cc] * p;
    }
  }

  const float SC = 1.0f / FXSCALE;
  float* pb = partial + (size_t)blockIdx.x * MROW;
#pragma unroll
  for (int cc = 0; cc < 8; ++cc) {
    pb[(cw + cc) * ADIM + 2 * l]     = a0[cc] * SC;
    pb[(cw + cc) * ADIM + 2 * l + 1] = a1[cc] * SC;
    if (l < 3) pb[(cw + cc) * ADIM + 128 + l] = a2[cc] * SC;
  }
}

// ---------------- tail MLP with fused partial-reduce (replaces reduce_kernel) ----------------
__global__ __launch_bounds__(1024) void final_kernel(
    const float* __restrict__ partial, const float* __restrict__ pos,
    const float* __restrict__ locT, const float* __restrict__ loc_b,
    const float* __restrict__ globT, const float* __restrict__ glob_b,
    const float* __restrict__ d1T, const float* __restrict__ d1b,
    const float* __restrict__ d2T, const float* __restrict__ d2b,
    const float* __restrict__ d3T, const float* __restrict__ d3b,
    float* __restrict__ out) {
  int c = blockIdx.x, t = threadIdx.x;
  int wv = t >> 6, ln = t & 63;

  __shared__ float sw[16][3];
  __shared__ float possum[3];
  __shared__ float r4[544];      // 4-way partial fold per dim
  __shared__ float msh[144];
  __shared__ float ttsh[256];
  __shared__ float ush[384];
  __shared__ float ash[256];
  __shared__ float bvsh[128];
  __shared__ float ptl2[4352];

  // --- pos sum ---
  {
    const float* pr = pos + ((size_t)c * PTSC + t) * 3;
    float s0 = pr[0], s1 = pr[1], s2 = pr[2];
#pragma unroll
    for (int m_ = 32; m_ > 0; m_ >>= 1) {
      s0 += __shfl_xor(s0, m_);
      s1 += __shfl_xor(s1, m_);
      s2 += __shfl_xor(s2, m_);
    }
    if (ln == 0) { sw[wv][0] = s0; sw[wv][1] = s1; sw[wv][2] = s2; }
  }
  // --- fused partial reduce: 4 threads per dim, 64 partial-blocks each ---
  {
    int dd = t >> 2, qq = t & 3;
    if (dd < 132) {
      float s = 0.f;
      int b0 = qq * 64;
      const float* pp = partial + c * ADIM + dd;
      for (int bk = b0; bk < b0 + 64; ++bk)
        s += pp[(size_t)bk * MROW];
      r4[dd * 4 + qq] = s;
    }
  }
  __syncthreads();
  if (t < 48) {
    int d = t >> 4, idx = t & 15;
    float v = sw[idx][d];
#pragma unroll
    for (int m_ = 8; m_ > 0; m_ >>= 1) v += __shfl_xor(v, m_);
    if (idx == 0) possum[d] = v;
  }
  __syncthreads();

  if (t < 144) {
    if (t < 128) {
      float s = (r4[4 * t] + r4[4 * t + 1]) + (r4[4 * t + 2] + r4[4 * t + 3]);
      msh[t] = s * (1.0f / (float)PTSC);
    } else if (t < 131) {
      float s = (r4[4 * t] + r4[4 * t + 1]) + (r4[4 * t + 2] + r4[4 * t + 3]);
      msh[t] = (s - possum[t - 128]) * (1.0f / (float)PTSC);
    } else {
      msh[t] = 0.f;   // pad rows (weights read in globT region, x0)
    }
  }
  __syncthreads();

  // --- loc: O=256, K=144(pad), ksplit=16 (p=wave), og=lane, 9 batched float4 loads ---
  {
    int p = wv, og = ln;
    float4 wvv[9];
#pragma unroll
    for (int j = 0; j < 9; ++j) {
      int k = p * 9 + j;
      wvv[j] = *reinterpret_cast<const float4*>(locT + (size_t)k * 256 + og * 4);
    }
    float a0, a1, a2, a3;
    if (p == 0) {
      float4 b = *reinterpret_cast<const float4*>(loc_b + og * 4);
      a0 = b.x; a1 = b.y; a2 = b.z; a3 = b.w;
    } else { a0 = a1 = a2 = a3 = 0.f; }
#pragma unroll
    for (int j = 0; j < 9; ++j) {
      float x = msh[p * 9 + j];
      a0 += wvv[j].x * x; a1 += wvv[j].y * x; a2 += wvv[j].z * x; a3 += wvv[j].w * x;
    }
    ptl2[(p * 4 + 0) * 66 + og] = a0;
    ptl2[(p * 4 + 1) * 66 + og] = a1;
    ptl2[(p * 4 + 2) * 66 + og] = a2;
    ptl2[(p * 4 + 3) * 66 + og] = a3;
  }
  __syncthreads();
  if (t < 256) {
    int og = t >> 2, sub = t & 3;
    float s = 0.f;
#pragma unroll
    for (int p = 0; p < 16; ++p) s += ptl2[(p * 4 + sub) * 66 + og];
    ttsh[t] = s;
  }
  __syncthreads();

  // --- glob: O=384, K=256, ksplit=8, og=0..95, 4 batches of 8 float4 loads ---
  if (t < 768) {
    int p = t / 96, og = t - p * 96;
    float a0, a1, a2, a3;
    if (p == 0) {
      float4 b = *reinterpret_cast<const float4*>(glob_b + og * 4);
      a0 = b.x; a1 = b.y; a2 = b.z; a3 = b.w;
    } else { a0 = a1 = a2 = a3 = 0.f; }
#pragma unroll
    for (int B = 0; B < 4; ++B) {
      float4 wvv[8];
#pragma unroll
      for (int j = 0; j < 8; ++j) {
        int k = p * 32 + B * 8 + j;
        wvv[j] = *reinterpret_cast<const float4*>(globT + (size_t)k * 384 + og * 4);
      }
#pragma unroll
      for (int j = 0; j < 8; ++j) {
        float x = ttsh[p * 32 + B * 8 + j];
        a0 += wvv[j].x * x; a1 += wvv[j].y * x; a2 += wvv[j].z * x; a3 += wvv[j].w * x;
      }
    }
    ptl2[(p * 4 + 0) * 98 + og] = a0;
    ptl2[(p * 4 + 1) * 98 + og] = a1;
    ptl2[(p * 4 + 2) * 98 + og] = a2;
    ptl2[(p * 4 + 3) * 98 + og] = a3;
  }
  __syncthreads();
  if (t < 384) {
    int og = t >> 2, sub = t & 3;
    float s = 0.f;
#pragma unroll
    for (int p = 0; p < 8; ++p) s += ptl2[(p * 4 + sub) * 98 + og];
    ush[t] = s;
  }
  __syncthreads();

  // --- d1: O=256, K=384, ksplit=16, 3 batches of 8 float4 loads, tanh ---
  {
    int p = wv, og = ln;
    float a0, a1, a2, a3;
    if (p == 0) {
      float4 b = *reinterpret_cast<const float4*>(d1b + og * 4);
      a0 = b.x; a1 = b.y; a2 = b.z; a3 = b.w;
    } else { a0 = a1 = a2 = a3 = 0.f; }
#pragma unroll
    for (int B = 0; B < 3; ++B) {
      float4 wvv[8];
#pragma unroll
      for (int j = 0; j < 8; ++j) {
        int k = p * 24 + B * 8 + j;
        wvv[j] = *reinterpret_cast<const float4*>(d1T + (size_t)k * 256 + og * 4);
      }
#pragma unroll
      for (int j = 0; j < 8; ++j) {
        float x = ush[p * 24 + B * 8 + j];
        a0 += wvv[j].x * x; a1 += wvv[j].y * x; a2 += wvv[j].z * x; a3 += wvv[j].w * x;
      }
    }
    ptl2[(p * 4 + 0) * 66 + og] = a0;
    ptl2[(p * 4 + 1) * 66 + og] = a1;
    ptl2[(p * 4 + 2) * 66 + og] = a2;
    ptl2[(p * 4 + 3) * 66 + og] = a3;
  }
  __syncthreads();
  if (t < 256) {
    int og = t >> 2, sub = t & 3;
    float s = 0.f;
#pragma unroll
    for (int p = 0; p < 16; ++p) s += ptl2[(p * 4 + sub) * 66 + og];
    ash[t] = tanhf(s);
  }
  __syncthreads();

  // --- d2: O=128, K=256, ksplit=32, og=0..31, 8 batched float4 loads, tanh ---
  {
    int p = t >> 5, og = t & 31;
    float4 wvv[8];
#pragma unroll
    for (int j = 0; j < 8; ++j) {
      int k = p * 8 + j;
      wvv[j] = *reinterpret_cast<const float4*>(d2T + (size_t)k * 128 + og * 4);
    }
    float a0, a1, a2, a3;
    if (p == 0) {
      float4 b = *reinterpret_cast<const float4*>(d2b + og * 4);
      a0 = b.x; a1 = b.y; a2 = b.z; a3 = b.w;
    } else { a0 = a1 = a2 = a3 = 0.f; }
#pragma unroll
    for (int j = 0; j < 8; ++j) {
      float x = ash[p * 8 + j];
      a0 += wvv[j].x * x; a1 += wvv[j].y * x; a2 += wvv[j].z * x; a3 += wvv[j].w * x;
    }
    ptl2[(p * 4 + 0) * 34 + og] = a0;
    ptl2[(p * 4 + 1) * 34 + og] = a1;
    ptl2[(p * 4 + 2) * 34 + og] = a2;
    ptl2[(p * 4 + 3) * 34 + og] = a3;
  }
  __syncthreads();
  if (t < 128) {
    int og = t >> 2, sub = t & 3;
    float s = 0.f;
#pragma unroll
    for (int p = 0; p < 32; ++p) s += ptl2[(p * 4 + sub) * 34 + og];
    bvsh[t] = tanhf(s);
  }
  __syncthreads();

  // --- d3: O=16, K=128, one wave per output ---
  {
    int o = wv, k = ln;
    if (o < 16) {
      float acc = d3T[k * 16 + o] * bvsh[k] + d3T[(k + 64) * 16 + o] * bvsh[k + 64];
#pragma unroll
      for (int m_ = 32; m_ > 0; m_ >>= 1) acc += __shfl_xor(acc, m_);
      if (ln == 0) out[c * 16 + o] = acc + d3b[o];
    }
  }
}

extern "C" void kernel_launch(void* const* d_in, const int* in_sizes, int n_in,
                              void* d_out, int out_size, void* d_ws, size_t ws_size,
                              hipStream_t stream) {
  const float* pos    = (const float*)d_in[0];
  const int*   ei     = (const int*)d_in[1];
  const float* enc1_w = (const float*)d_in[2];
  const float* enc1_b = (const float*)d_in[3];
  const float* enc2_w = (const float*)d_in[4];
  const float* enc2_b = (const float*)d_in[5];
  const float* enc3_w = (const float*)d_in[6];
  const float* enc3_b = (const float*)d_in[7];
  const float* loc_w  = (const float*)d_in[8];
  const float* loc_b  = (const float*)d_in[9];
  const float* glob_w = (const float*)d_in[10];
  const float* glob_b = (const float*)d_in[11];
  const float* d1w    = (const float*)d_in[12];
  const float* d1b    = (const float*)d_in[13];
  const float* d2w    = (const float*)d_in[14];
  const float* d2b    = (const float*)d_in[15];
  const float* d3w    = (const float*)d_in[16];
  const float* d3b    = (const float*)d_in[17];
  float* out = (float*)d_out;

  // workspace layout (bytes, 256B-aligned)
  char* ws = (char*)d_ws;
  size_t o = 0;
  __hip_bfloat16* xb = (__hip_bfloat16*)(ws + o); o += 8388608;     // N*128 bf16
  int*   ai    = (int*)  (ws + o); o += 4194304;                    // N*32 i32
  int*   cnt   = (int*)  (ws + o); o += 131072;
  int*   invwi = (int*)  (ws + o); o += 131072;
  float* Macc  = (float*)(ws + o); o += 17408;                      // unused (kept for layout)
  float* w2T   = (float*)(ws + o); o += 16384;
  float* w3T   = (float*)(ws + o); o += 32768;
  float* locT  = (float*)(ws + o); o += 134144;
  float* globT = (float*)(ws + o); o += 393216;
  float* d1T   = (float*)(ws + o); o += 393216;
  float* d2T   = (float*)(ws + o); o += 131072;
  float* d3T   = (float*)(ws + o); o += 8192;
  float* partial = (float*)(ws + o);                                // NBLK*MROW f32
  (void)ws_size;
  (void)Macc;

  prep_kernel<<<1211, 256, 0, stream>>>(enc2_w, enc3_w, loc_w, glob_w, d1w, d2w, d3w,
                                        w2T, w3T, locT, globT, d1T, d2T, d3T, cnt);
  hist_kernel<<<EEDGES / 1024, 256, 0, stream>>>(ei, cnt);
  invwi_kernel<<<NPTS / 256, 256, 0, stream>>>(cnt, invwi, ai);
  enc_ascatter_kernel<<<EEDGES / 1024 + NPTS / 32, 256, 0, stream>>>(
      ei, invwi, ai, pos, enc1_w, enc1_b, w2T, enc2_b, w3T, enc3_b, xb);
  contract_kernel<<<NBLK, 256, 0, stream>>>((const ushort*)xb, pos, ai, partial);
  final_kernel<<<NCLOUD, 1024, 0, stream>>>(partial, pos, locT, loc_b, globT, glob_b,
                                            d1T, d1b, d2T, d2b, d3T, d3b, out);
}